// Round 1
// baseline (432.287 us; speedup 1.0000x reference)
//
#include <hip/hip_runtime.h>
#include <stdint.h>

typedef unsigned int u32;
typedef unsigned short u16;
typedef __attribute__((ext_vector_type(8))) short bf16x8;   // 8 bf16 = 4 VGPRs
typedef __attribute__((ext_vector_type(4))) float f32x4;    // MFMA C/D frag

#define B_ 4
#define S_ 4096
#define D_ 512
#define SCALE_ 0.04419417382415922f   // 512^-0.5

// ---------- helpers ----------
__device__ __forceinline__ u16 f2b(float f) {               // fp32 -> bf16 RNE
  u32 u = __builtin_bit_cast(u32, f);
  return (u16)((u + 0x7FFFu + ((u >> 16) & 1u)) >> 16);
}
__device__ __forceinline__ float b2f(u16 h) {
  u32 u = ((u32)h) << 16;
  return __builtin_bit_cast(float, u);
}
// async global->LDS, 16B/lane, dst = lds + lane*16 (wave-uniform lds base)
__device__ __forceinline__ void gld16(const void* g, void* l) {
  __builtin_amdgcn_global_load_lds(
      (const __attribute__((address_space(1))) u32*)g,
      (__attribute__((address_space(3))) u32*)l, 16, 0, 0);
}

// =====================================================================
// Kernel 1: Q = X @ W^T (NT gemm, bf16 MFMA), writes Qrow [B*S][D] bf16
// and Qt [B][D][S] bf16 (transposed copy -> V tiles for flash).
// Block: 256 thr (4 waves), 64 rows x 512 cols, K-chunks of 64.
// =====================================================================
__global__ __launch_bounds__(256, 1) void qproj(
    const float* __restrict__ X, const float* __restrict__ W,
    u16* __restrict__ Qr, u16* __restrict__ Qt) {
  // W chunk: 512 rows x 64 cols bf16, rows = 8 blocks of 16B, mod-8 rotated
  __shared__ __align__(16) u16 Wt[512 * 64];
  const int tid = threadIdx.x;
  const int wave = tid >> 6, lane = tid & 63;
  const int m16 = lane & 15, quad = lane >> 4;
  const int r0 = blockIdx.x * 64;

  f32x4 acc[32];
#pragma unroll
  for (int i = 0; i < 32; ++i) acc[i] = f32x4{};

  const float* xrow = X + (size_t)(r0 + wave * 16 + m16) * D_;

  for (int kc = 0; kc < 8; ++kc) {
    // ---- stage W[:, kc*64 .. +63] as bf16, data block bl -> LDS block (bl+e)&7
#pragma unroll
    for (int rr = 0; rr < 2; ++rr) {
      int e = tid + rr * 256;
      const float* src = W + (size_t)e * D_ + kc * 64;
#pragma unroll
      for (int bl = 0; bl < 8; ++bl) {
        float4 a = ((const float4*)src)[bl * 2];
        float4 b = ((const float4*)src)[bl * 2 + 1];
        bf16x8 v;
        v[0] = (short)f2b(a.x); v[1] = (short)f2b(a.y);
        v[2] = (short)f2b(a.z); v[3] = (short)f2b(a.w);
        v[4] = (short)f2b(b.x); v[5] = (short)f2b(b.y);
        v[6] = (short)f2b(b.z); v[7] = (short)f2b(b.w);
        *(bf16x8*)(&Wt[e * 64 + ((bl + e) & 7) * 8]) = v;
      }
    }
    __syncthreads();
    // ---- compute: 2 MFMA k-steps of 32
#pragma unroll
    for (int kk = 0; kk < 2; ++kk) {
      const float* ap = xrow + kc * 64 + kk * 32 + quad * 8;
      float4 a0 = ((const float4*)ap)[0];
      float4 a1 = ((const float4*)ap)[1];
      bf16x8 af;
      af[0] = (short)f2b(a0.x); af[1] = (short)f2b(a0.y);
      af[2] = (short)f2b(a0.z); af[3] = (short)f2b(a0.w);
      af[4] = (short)f2b(a1.x); af[5] = (short)f2b(a1.y);
      af[6] = (short)f2b(a1.z); af[7] = (short)f2b(a1.w);
      int jb = quad + 4 * kk;  // data block 0..7
#pragma unroll
      for (int nt = 0; nt < 32; ++nt) {
        int e = m16 + nt * 16;
        bf16x8 bf = *(const bf16x8*)(&Wt[e * 64 + ((jb + e) & 7) * 8]);
        acc[nt] = __builtin_amdgcn_mfma_f32_16x16x32_bf16(af, bf, acc[nt], 0, 0, 0);
      }
    }
    __syncthreads();
  }
  // ---- epilogue: C/D layout row = quad*4+r, col = m16+16*nt
  const int b = r0 >> 12;                       // 4096 rows per batch
  const int s0 = (r0 & (S_ - 1)) + wave * 16 + quad * 4;
  const int grow = r0 + wave * 16 + quad * 4;
#pragma unroll
  for (int nt = 0; nt < 32; ++nt) {
    int e = nt * 16 + m16;
    u16 h0 = f2b(acc[nt][0]), h1 = f2b(acc[nt][1]);
    u16 h2 = f2b(acc[nt][2]), h3 = f2b(acc[nt][3]);
    Qr[(size_t)(grow + 0) * D_ + e] = h0;
    Qr[(size_t)(grow + 1) * D_ + e] = h1;
    Qr[(size_t)(grow + 2) * D_ + e] = h2;
    Qr[(size_t)(grow + 3) * D_ + e] = h3;
    uint2 pv;
    pv.x = (u32)h0 | ((u32)h1 << 16);
    pv.y = (u32)h2 | ((u32)h3 << 16);
    *(uint2*)(&Qt[((size_t)(b * D_ + e)) * S_ + s0]) = pv;   // 8B aligned (s0 % 4 == 0)
  }
}

// =====================================================================
// Kernel 2: flash attention. Q=K=V=Qrow (V read from Qt, transposed).
// Block = (qtile of 64 rows, batch); 4 waves x 16 q-rows; Bc = 64 keys/iter.
// LDS: Kt 64KB + Vt 64KB + per-wave P 11KB = 139KB -> 1 block/CU (grid=256).
// =====================================================================
__global__ __launch_bounds__(256, 1) void flashattn(
    const u16* __restrict__ Qrow, const u16* __restrict__ Qt,
    float* __restrict__ Out) {
  __shared__ __align__(16) u16 Kt[64 * 512];      // [key n][d], mod-8 rotated blocks
  __shared__ __align__(16) u16 Vt[512 * 64];      // [d][key c], mod-8 rotated blocks
  __shared__ __align__(16) u16 Pl[4][16 * 88];    // per-wave P [qrow][key], stride 88

  const int tid = threadIdx.x;
  const int wave = tid >> 6, lane = tid & 63;
  const int m16 = lane & 15, quad = lane >> 4;
  const int qt = blockIdx.x, bb = blockIdx.y;
  const u16* Qb  = Qrow + (size_t)bb * S_ * D_;
  const u16* Qtb = Qt   + (size_t)bb * D_ * S_;

  // Q A-fragments: 16 k-steps, lane holds Q[m16][ks*32 + quad*8 + j]
  bf16x8 qf[16];
  {
    const u16* qp = Qb + (size_t)(qt * 64 + wave * 16 + m16) * D_ + quad * 8;
#pragma unroll
    for (int ks = 0; ks < 16; ++ks) qf[ks] = *(const bf16x8*)(qp + ks * 32);
  }

  f32x4 o[32];
#pragma unroll
  for (int i = 0; i < 32; ++i) o[i] = f32x4{};
  float mrow[4] = {-1e30f, -1e30f, -1e30f, -1e30f};
  float lrow[4] = {0.f, 0.f, 0.f, 0.f};
  u16* pw = &Pl[wave][0];

  for (int kt = 0; kt < 64; ++kt) {
    // ---- stage K tile: row n = one wave-instr (1KB), block i <- global (i&~7)|((i+n)&7)
    {
      const u16* src = Qb + (size_t)(kt * 64) * D_;
#pragma unroll
      for (int t = 0; t < 16; ++t) {
        int n = wave * 16 + t;
        int gb = (lane & ~7) | ((lane + n) & 7);
        gld16(src + (size_t)n * D_ + gb * 8, &Kt[n * 512]);
      }
      // ---- stage V^T tile: 8 d-rows per wave-instr, block (lane&7) <- global ((lane&7)+d)&7
      const u16* vsrc = Qtb + kt * 64;
#pragma unroll
      for (int t = 0; t < 16; ++t) {
        int d0 = (wave * 16 + t) * 8;
        int d  = d0 + (lane >> 3);
        int gb = ((lane & 7) + d) & 7;
        gld16(vsrc + (size_t)d * S_ + gb * 8, &Vt[d0 * 64]);
      }
    }
    __syncthreads();   // compiler emits vmcnt(0) drain before barrier

    // ---- S = Q K^T (raw scores; SCALE folded into exp)
    f32x4 sv[4];
#pragma unroll
    for (int nt = 0; nt < 4; ++nt) {
      f32x4 a = f32x4{};
      int n = m16 + nt * 16;
      const u16* kr = &Kt[n * 512];
#pragma unroll
      for (int ks = 0; ks < 16; ++ks) {
        int jb = quad + 4 * ks;
        int ib = (jb & ~7) | ((jb - n) & 7);
        bf16x8 bf = *(const bf16x8*)(kr + ib * 8);
        a = __builtin_amdgcn_mfma_f32_16x16x32_bf16(qf[ks], bf, a, 0, 0, 0);
      }
      sv[nt] = a;
    }

    // ---- online softmax; C-layout: lane holds rows quad*4+r, col m16+16*nt
    float mnew[4], alpha[4];
    int grew = 0;
#pragma unroll
    for (int r = 0; r < 4; ++r) {
      float t = fmaxf(fmaxf(sv[0][r], sv[1][r]), fmaxf(sv[2][r], sv[3][r]));
      t = fmaxf(t, __shfl_xor(t, 1));
      t = fmaxf(t, __shfl_xor(t, 2));
      t = fmaxf(t, __shfl_xor(t, 4));
      t = fmaxf(t, __shfl_xor(t, 8));   // row max across the quad's 16 lanes
      float mn = fmaxf(mrow[r], t);
      mnew[r] = mn;
      grew |= (mn > mrow[r]);
      alpha[r] = __expf((mrow[r] - mn) * SCALE_);
    }
    float psum[4] = {0.f, 0.f, 0.f, 0.f};
#pragma unroll
    for (int nt = 0; nt < 4; ++nt) {
#pragma unroll
      for (int r = 0; r < 4; ++r) {
        float p = __expf((sv[nt][r] - mnew[r]) * SCALE_);
        u16 h = f2b(p);
        psum[r] += b2f(h);               // l from quantized P: errors cancel in O/l
        pw[(quad * 4 + r) * 88 + nt * 16 + m16] = h;
      }
    }
#pragma unroll
    for (int r = 0; r < 4; ++r) {
      float t = psum[r];
      t += __shfl_xor(t, 1);
      t += __shfl_xor(t, 2);
      t += __shfl_xor(t, 4);
      t += __shfl_xor(t, 8);
      lrow[r] = lrow[r] * alpha[r] + t;
      mrow[r] = mnew[r];
    }
    if (__ballot(grew) != 0ull) {        // skip O rescale when max didn't move
#pragma unroll
      for (int dt = 0; dt < 32; ++dt) {
        o[dt][0] *= alpha[0]; o[dt][1] *= alpha[1];
        o[dt][2] *= alpha[2]; o[dt][3] *= alpha[3];
      }
    }

    // ---- O += P V  (A = P from per-wave LDS, B = V^T rows from Vt)
#pragma unroll
    for (int ks2 = 0; ks2 < 2; ++ks2) {
      bf16x8 pf = *(const bf16x8*)(pw + m16 * 88 + ks2 * 32 + quad * 8);
      int ib = ((quad + 4 * ks2) - m16) & 7;   // d = m16 (mod 8), dt*16 = 0 (mod 8)
#pragma unroll
      for (int dt = 0; dt < 32; ++dt) {
        int d = m16 + dt * 16;
        bf16x8 vf = *(const bf16x8*)(&Vt[d * 64 + ib * 8]);
        o[dt] = __builtin_amdgcn_mfma_f32_16x16x32_bf16(pf, vf, o[dt], 0, 0, 0);
      }
    }
    __syncthreads();   // protect Kt/Vt before next stage
  }

  // ---- epilogue: y = O / l, fp32 out
  float inv[4];
#pragma unroll
  for (int r = 0; r < 4; ++r) inv[r] = 1.f / lrow[r];
  const int row0 = qt * 64 + wave * 16 + quad * 4;
#pragma unroll
  for (int dt = 0; dt < 32; ++dt) {
    int col = dt * 16 + m16;
    size_t base = ((size_t)bb * S_ + row0) * D_ + col;
    Out[base]           = o[dt][0] * inv[0];
    Out[base + D_]      = o[dt][1] * inv[1];
    Out[base + 2 * D_]  = o[dt][2] * inv[2];
    Out[base + 3 * D_]  = o[dt][3] * inv[3];
  }
}

// =====================================================================
extern "C" void kernel_launch(void* const* d_in, const int* in_sizes, int n_in,
                              void* d_out, int out_size, void* d_ws, size_t ws_size,
                              hipStream_t stream) {
  (void)in_sizes; (void)n_in; (void)out_size; (void)ws_size;
  const float* X = (const float*)d_in[0];
  const float* W = (const float*)d_in[1];
  float* Out = (float*)d_out;
  u16* Qr = (u16*)d_ws;                                   // [B*S][D] bf16, 16.8 MB
  u16* Qt = Qr + (size_t)B_ * S_ * D_;                    // [B][D][S] bf16, 16.8 MB

  qproj<<<dim3(256), dim3(256), 0, stream>>>(X, W, Qr, Qt);
  flashattn<<<dim3(64, 4), dim3(256), 0, stream>>>(Qr, Qt, Out);
}

// Round 2
// 356.025 us; speedup vs baseline: 1.2142x; 1.2142x over previous
//
#include <hip/hip_runtime.h>
#include <stdint.h>

typedef unsigned int u32;
typedef unsigned short u16;
typedef __attribute__((ext_vector_type(8))) short bf16x8;   // 8 bf16 = 4 VGPRs
typedef __attribute__((ext_vector_type(4))) float f32x4;    // MFMA C/D frag

#define B_ 4
#define S_ 4096
#define D_ 512
#define SCALE_ 0.04419417382415922f   // 512^-0.5

// ---------- helpers ----------
__device__ __forceinline__ u16 f2b(float f) {               // fp32 -> bf16 RNE (exact)
  u32 u = __builtin_bit_cast(u32, f);
  return (u16)((u + 0x7FFFu + ((u >> 16) & 1u)) >> 16);
}
__device__ __forceinline__ u16 f2b_fast(float f) {          // RNE sans tie-break (2 ops)
  u32 u = __builtin_bit_cast(u32, f);
  return (u16)((u + 0x8000u) >> 16);
}
// async global->LDS, 16B/lane, dst = lds + lane*16 (wave-uniform lds base)
__device__ __forceinline__ void gld16(const void* g, void* l) {
  __builtin_amdgcn_global_load_lds(
      (const __attribute__((address_space(1))) u32*)g,
      (__attribute__((address_space(3))) u32*)l, 16, 0, 0);
}

// =====================================================================
// Kernel 0: Wb = bf16(W), one pass. 256x256 threads, 4 elems/thread.
// =====================================================================
__global__ __launch_bounds__(256, 1) void qprep(
    const float* __restrict__ W, u16* __restrict__ Wb) {
  int i = (blockIdx.x * 256 + threadIdx.x) * 4;
  float4 a = *(const float4*)(W + i);
  ushort4 o;
  o.x = f2b(a.x); o.y = f2b(a.y); o.z = f2b(a.z); o.w = f2b(a.w);
  *(ushort4*)(Wb + i) = o;
}

// =====================================================================
// Kernel 1: Q = X @ W^T (NT gemm, bf16 MFMA), writes Qrow [B*S][D] bf16
// and Qt [B][D][S] bf16 (transposed copy -> V tiles for flash).
// Block: 256 thr (4 waves), 64 rows x 512 cols. W staged from pre-cast
// Wb via global_load_lds into double-buffered LDS (DMA overlaps MFMA).
// X A-fragments hoisted to registers before the loop.
// =====================================================================
__global__ __launch_bounds__(256, 1) void qproj(
    const float* __restrict__ X, const u16* __restrict__ Wb,
    u16* __restrict__ Qr, u16* __restrict__ Qt) {
  // chunk = W[:, kc*64 .. +63] bf16: 512 rows x 64 cols, rows = 8 16B-blocks,
  // global block j of row e lands at LDS block (j+e)&7 (mod-8 rotation).
  __shared__ __align__(16) u16 Wt[2][512 * 64];              // 2 x 64 KB
  const int tid = threadIdx.x;
  const int wave = tid >> 6, lane = tid & 63;
  const int m16 = lane & 15, quad = lane >> 4;
  const int r0 = blockIdx.x * 64;

  // ---- hoist X row -> 16 bf16 A-fragments (A[m16][ks*32 + quad*8 + j])
  const float* xrow = X + (size_t)(r0 + wave * 16 + m16) * D_;
  bf16x8 af[16];
#pragma unroll
  for (int ks = 0; ks < 16; ++ks) {
    const float* ap = xrow + ks * 32 + quad * 8;
    float4 a0 = ((const float4*)ap)[0];
    float4 a1 = ((const float4*)ap)[1];
    bf16x8 v;
    v[0] = (short)f2b(a0.x); v[1] = (short)f2b(a0.y);
    v[2] = (short)f2b(a0.z); v[3] = (short)f2b(a0.w);
    v[4] = (short)f2b(a1.x); v[5] = (short)f2b(a1.y);
    v[6] = (short)f2b(a1.z); v[7] = (short)f2b(a1.w);
    af[ks] = v;
  }

  f32x4 acc[32];
#pragma unroll
  for (int i = 0; i < 32; ++i) acc[i] = f32x4{};

  // ---- stage chunk kc into Wt[buf]: 16 gld16 per wave, 8 rows each
  auto stage = [&](int kc, int buf) {
#pragma unroll
    for (int t = 0; t < 16; ++t) {
      int e0 = (wave * 16 + t) * 8;
      int e = e0 + (lane >> 3);
      int gb = ((lane & 7) - e) & 7;                     // global block for LDS block lane&7
      gld16(Wb + (size_t)e * D_ + kc * 64 + gb * 8, &Wt[buf][e0 * 64]);
    }
  };

  stage(0, 0);
  __syncthreads();                                       // drains chunk 0

  for (int kc = 0; kc < 8; ++kc) {
    if (kc < 7) stage(kc + 1, (kc + 1) & 1);             // DMA overlaps MFMAs below
    const u16* wb = &Wt[kc & 1][0];
#pragma unroll
    for (int kk = 0; kk < 2; ++kk) {
      int jb = quad + 4 * kk;                            // data block 0..7
      bf16x8 a = af[kc * 2 + kk];
#pragma unroll
      for (int nt = 0; nt < 32; ++nt) {
        int e = m16 + nt * 16;
        bf16x8 bf = *(const bf16x8*)(wb + e * 64 + ((jb + e) & 7) * 8);
        acc[nt] = __builtin_amdgcn_mfma_f32_16x16x32_bf16(a, bf, acc[nt], 0, 0, 0);
      }
    }
    __syncthreads();                                     // drains chunk kc+1, protects Wt[kc&1]
  }

  // ---- epilogue: C/D layout row = quad*4+r, col = m16+16*nt
  const int b = r0 >> 12;                                // 4096 rows per batch
  const int s0 = (r0 & (S_ - 1)) + wave * 16 + quad * 4;
  const int grow = r0 + wave * 16 + quad * 4;
#pragma unroll
  for (int nt = 0; nt < 32; ++nt) {
    int e = nt * 16 + m16;
    u16 h0 = f2b(acc[nt][0]), h1 = f2b(acc[nt][1]);
    u16 h2 = f2b(acc[nt][2]), h3 = f2b(acc[nt][3]);
    Qr[(size_t)(grow + 0) * D_ + e] = h0;
    Qr[(size_t)(grow + 1) * D_ + e] = h1;
    Qr[(size_t)(grow + 2) * D_ + e] = h2;
    Qr[(size_t)(grow + 3) * D_ + e] = h3;
    uint2 pv;
    pv.x = (u32)h0 | ((u32)h1 << 16);
    pv.y = (u32)h2 | ((u32)h3 << 16);
    *(uint2*)(&Qt[((size_t)(b * D_ + e)) * S_ + s0]) = pv;  // 8B aligned (s0 % 4 == 0)
  }
}

// =====================================================================
// Kernel 2: flash attention, phase-pipelined single-buffer staging.
// Per iter: [issue V[kt] DMA] S-MFMA/softmax [barrier drains V]
//           [issue K[kt+1] DMA] rescale + PV-MFMA [barrier drains K].
// l tracked as a 33rd PV accumulator against a constant ones B-frag.
// =====================================================================
__global__ __launch_bounds__(256, 1) void flashattn(
    const u16* __restrict__ Qrow, const u16* __restrict__ Qt,
    float* __restrict__ Out) {
  __shared__ __align__(16) u16 Kt[64 * 512];      // [key n][d], mod-8 rotated blocks
  __shared__ __align__(16) u16 Vt[512 * 64];      // [d][key c], mod-8 rotated blocks
  __shared__ __align__(16) u16 Pl[4][16 * 88];    // per-wave P [qrow][key], stride 88

  const int tid = threadIdx.x;
  const int wave = tid >> 6, lane = tid & 63;
  const int m16 = lane & 15, quad = lane >> 4;
  const int qt = blockIdx.x, bb = blockIdx.y;
  const u16* Qb  = Qrow + (size_t)bb * S_ * D_;
  const u16* Qtb = Qt   + (size_t)bb * D_ * S_;

  auto stageK = [&](int kt) {       // row n = one wave-instr (1KB), rotated blocks
    const u16* src = Qb + (size_t)(kt * 64) * D_;
#pragma unroll
    for (int t = 0; t < 16; ++t) {
      int n = wave * 16 + t;
      int gb = (lane & ~7) | ((lane + n) & 7);
      gld16(src + (size_t)n * D_ + gb * 8, &Kt[n * 512]);
    }
  };
  auto stageV = [&](int kt) {       // 8 d-rows per wave-instr, rotated blocks
    const u16* vsrc = Qtb + kt * 64;
#pragma unroll
    for (int t = 0; t < 16; ++t) {
      int d0 = (wave * 16 + t) * 8;
      int d  = d0 + (lane >> 3);
      int gb = ((lane & 7) + d) & 7;
      gld16(vsrc + (size_t)d * S_ + gb * 8, &Vt[d0 * 64]);
    }
  };

  // Q A-fragments: lane holds Q[m16][ks*32 + quad*8 + j]
  bf16x8 qf[16];
  {
    const u16* qp = Qb + (size_t)(qt * 64 + wave * 16 + m16) * D_ + quad * 8;
#pragma unroll
    for (int ks = 0; ks < 16; ++ks) qf[ks] = *(const bf16x8*)(qp + ks * 32);
  }

  bf16x8 onesf;                     // constant B-frag of 1.0 for the l-column
#pragma unroll
  for (int j = 0; j < 8; ++j) onesf[j] = (short)0x3F80;

  f32x4 o[32];
#pragma unroll
  for (int i = 0; i < 32; ++i) o[i] = f32x4{};
  f32x4 ol = f32x4{};               // row-sums of P with alpha recurrence == l
  float mrow[4] = {-1e30f, -1e30f, -1e30f, -1e30f};
  u16* pw = &Pl[wave][0];

  stageK(0);
  __syncthreads();                  // drains K[0]

  for (int kt = 0; kt < 64; ++kt) {
    // ======== phase A: V[kt] streams while S = Q K^T computes ========
    stageV(kt);

    f32x4 sv[4];
#pragma unroll
    for (int nt = 0; nt < 4; ++nt) {
      f32x4 a = f32x4{};
      int n = m16 + nt * 16;
      const u16* kr = &Kt[n * 512];
#pragma unroll
      for (int ks = 0; ks < 16; ++ks) {
        int jb = quad + 4 * ks;
        int ib = (jb & ~7) | ((jb - n) & 7);
        bf16x8 bf = *(const bf16x8*)(kr + ib * 8);
        a = __builtin_amdgcn_mfma_f32_16x16x32_bf16(qf[ks], bf, a, 0, 0, 0);
      }
      sv[nt] = a;
    }

    // online softmax; C-layout: lane holds rows quad*4+r, col m16+16*nt
    float mnew[4], alpha[4];
    int grew = 0;
#pragma unroll
    for (int r = 0; r < 4; ++r) {
      float t = fmaxf(fmaxf(sv[0][r], sv[1][r]), fmaxf(sv[2][r], sv[3][r]));
      t = fmaxf(t, __shfl_xor(t, 1));
      t = fmaxf(t, __shfl_xor(t, 2));
      t = fmaxf(t, __shfl_xor(t, 4));
      t = fmaxf(t, __shfl_xor(t, 8));   // row max across the quad's 16 lanes
      float mn = fmaxf(mrow[r], t);
      mnew[r] = mn;
      grew |= (mn > mrow[r]);
      alpha[r] = __expf((mrow[r] - mn) * SCALE_);
      mrow[r] = mn;
    }
#pragma unroll
    for (int nt = 0; nt < 4; ++nt) {
#pragma unroll
      for (int r = 0; r < 4; ++r) {
        float p = __expf((sv[nt][r] - mnew[r]) * SCALE_);
        pw[(quad * 4 + r) * 88 + nt * 16 + m16] = f2b_fast(p);
      }
    }

    __syncthreads();                // drains V[kt]; P visible (same wave anyway)

    // ======== phase B: K[kt+1] streams while rescale + PV compute ========
    if (kt < 63) stageK(kt + 1);

    if (__ballot(grew) != 0ull) {   // skip O rescale when max didn't move
#pragma unroll
      for (int dt = 0; dt < 32; ++dt) {
        o[dt][0] *= alpha[0]; o[dt][1] *= alpha[1];
        o[dt][2] *= alpha[2]; o[dt][3] *= alpha[3];
      }
      ol[0] *= alpha[0]; ol[1] *= alpha[1];
      ol[2] *= alpha[2]; ol[3] *= alpha[3];
    }

#pragma unroll
    for (int ks2 = 0; ks2 < 2; ++ks2) {
      bf16x8 pf = *(const bf16x8*)(pw + m16 * 88 + ks2 * 32 + quad * 8);
      int ib = ((quad + 4 * ks2) - m16) & 7;   // d = m16 (mod 8)
#pragma unroll
      for (int dt = 0; dt < 32; ++dt) {
        int d = m16 + dt * 16;
        bf16x8 vf = *(const bf16x8*)(&Vt[d * 64 + ib * 8]);
        o[dt] = __builtin_amdgcn_mfma_f32_16x16x32_bf16(pf, vf, o[dt], 0, 0, 0);
      }
      ol = __builtin_amdgcn_mfma_f32_16x16x32_bf16(pf, onesf, ol, 0, 0, 0);
    }

    __syncthreads();                // drains K[kt+1]; Kt/Vt safe for next iter
  }

  // ---- epilogue: y = O / l, fp32 out (ol cols all equal the row-sum)
  float inv[4];
#pragma unroll
  for (int r = 0; r < 4; ++r) inv[r] = 1.f / ol[r];
  const int row0 = qt * 64 + wave * 16 + quad * 4;
#pragma unroll
  for (int dt = 0; dt < 32; ++dt) {
    int col = dt * 16 + m16;
    size_t base = ((size_t)bb * S_ + row0) * D_ + col;
    Out[base]           = o[dt][0] * inv[0];
    Out[base + D_]      = o[dt][1] * inv[1];
    Out[base + 2 * D_]  = o[dt][2] * inv[2];
    Out[base + 3 * D_]  = o[dt][3] * inv[3];
  }
}

// =====================================================================
extern "C" void kernel_launch(void* const* d_in, const int* in_sizes, int n_in,
                              void* d_out, int out_size, void* d_ws, size_t ws_size,
                              hipStream_t stream) {
  (void)in_sizes; (void)n_in; (void)out_size; (void)ws_size;
  const float* X = (const float*)d_in[0];
  const float* W = (const float*)d_in[1];
  float* Out = (float*)d_out;
  u16* Qr = (u16*)d_ws;                                   // [B*S][D] bf16, 16.8 MB
  u16* Qt = Qr + (size_t)B_ * S_ * D_;                    // [B][D][S] bf16, 16.8 MB
  u16* Wb = Qt + (size_t)B_ * D_ * S_;                    // [D][D]    bf16, 0.5 MB

  qprep<<<dim3(256), dim3(256), 0, stream>>>(W, Wb);
  qproj<<<dim3(256), dim3(256), 0, stream>>>(X, Wb, Qr, Qt);
  flashattn<<<dim3(64, 4), dim3(256), 0, stream>>>(Qr, Qt, Out);
}